// Round 4
// baseline (5578.668 us; speedup 1.0000x reference)
//
#include <hip/hip_runtime.h>
#include <hip/hip_bf16.h>

typedef _Float16 f16;
typedef __attribute__((ext_vector_type(8))) _Float16 f16x8;
typedef __attribute__((ext_vector_type(4))) float f32x4;

#define TT 128
#define LSTM_BLOCKS 128

__device__ __forceinline__ float sigmoidf_(float x) { return 1.0f / (1.0f + __expf(-x)); }

// ---------------------------------------------------------------------------
// fp32 -> fp16 convert (n multiple of 4)
__global__ __launch_bounds__(256) void k_f2h(const float* __restrict__ in,
                                             f16* __restrict__ out, long n4) {
  long i = (long)blockIdx.x * 256 + threadIdx.x;
  if (i >= n4) return;
  float4 v = ((const float4*)in)[i];
  out[i*4+0] = (f16)v.x; out[i*4+1] = (f16)v.y;
  out[i*4+2] = (f16)v.z; out[i*4+3] = (f16)v.w;
}

// gather rule_emb rows for init_prod -> fp16 (32 x 1024)
__global__ __launch_bounds__(256) void k_gather_prod(const float* __restrict__ rule_emb,
                                                     const int* __restrict__ init_prod,
                                                     f16* __restrict__ out) {
  int i = blockIdx.x * 256 + threadIdx.x;
  int b = i >> 10, k = i & 1023;
  out[i] = (f16)rule_emb[(long)init_prod[b] * 1024 + k];
}

// h0 -> fp16 into st slot 0 (st layout: [b][129][1024])
__global__ __launch_bounds__(256) void k_h0(const float* __restrict__ h0,
                                            f16* __restrict__ st) {
  int i = blockIdx.x * 256 + threadIdx.x;
  int b = i >> 10, k = i & 1023;
  st[(long)b * 129 * 1024 + k] = (f16)h0[i];
}

__global__ void k_zero(int* p) { if (threadIdx.x == 0) *p = 0; }

// (B, L=512, H=1024) fp32 -> outT (B, H, L) f16  AND  outN (B, L, H) f16
__global__ __launch_bounds__(256) void k_transpose(const float* __restrict__ in,
                                                   f16* __restrict__ outT,
                                                   f16* __restrict__ outN) {
  __shared__ float tile[32][33];
  const int b  = blockIdx.z;
  const int l0 = blockIdx.x * 32, h0 = blockIdx.y * 32;
  in   += (long)b * 512 * 1024;
  outT += (long)b * 1024 * 512;
  outN += (long)b * 512 * 1024;
  const int c = threadIdx.x & 31, r = threadIdx.x >> 5;
#pragma unroll
  for (int p = 0; p < 4; ++p) {
    float v = in[(long)(l0 + r + p*8) * 1024 + h0 + c];
    tile[r + p*8][c] = v;
    outN[(long)(l0 + r + p*8) * 1024 + h0 + c] = (f16)v;
  }
  __syncthreads();
#pragma unroll
  for (int p = 0; p < 4; ++p)
    outT[(long)(h0 + r + p*8) * 512 + l0 + c] = (f16)tile[c][r + p*8];
}

// ---------------------------------------------------------------------------
// fp16 MFMA GEMM: C[M,N] = act( A[M,K] @ B[N,K]^T + bias1 + bias2 )
// 128x128 tile, BK=32, register-prefetch double buffer.
// bmod: B K-index wraps mod bmod. zdiv: split-K, partials at outF+slice*sSl.
// ilv: outF column remap col -> (col&1023)*4 + (col>>10)  (gate-interleave).
__global__ __launch_bounds__(256) void k_gemm(
    const f16* __restrict__ A, long lda, long sA,
    const f16* __restrict__ B, long ldb, long sB,
    float* __restrict__ outF, long ldF, long sF, long sSl,
    f16* __restrict__ outH, long ldH, long sH,
    f16* __restrict__ outH2, long ldH2, long sH2,
    f16* __restrict__ out2, long ld2, long s2,
    const float* __restrict__ bias1, const float* __restrict__ bias2,
    int M, int N, int K, int act, int bmod, int zdiv, int ilv)
{
  __shared__ __align__(16) f16 As[128][40];
  __shared__ __align__(16) f16 Bs[128][40];
  const int tid = threadIdx.x;
  const int w = tid >> 6, lane = tid & 63;
  const int wm = (w & 1) * 64, wn = (w >> 1) * 64;
  const int lr = lane >> 4, lc = lane & 15;
  const long m0 = (long)blockIdx.x * 128;
  const long n0 = (long)blockIdx.y * 128;
  int z = blockIdx.z, batch = z, slice = 0, Ks = K;
  if (zdiv > 1) { batch = z / zdiv; slice = z - batch * zdiv; Ks = K / zdiv; }
  const long kbeg = (long)slice * Ks;
  A += (long)batch * sA;
  B += (long)batch * sB;

  const int rr = tid >> 2, sg = (tid & 3) * 8;
  const int nIt = Ks / 32;

  uint4 pa[2], pb[2];
  {
    long k = kbeg;
    long kb = bmod ? (k & (bmod - 1)) : k;
#pragma unroll
    for (int p = 0; p < 2; ++p) {
      int row = p * 64 + rr;
      uint4 va = {0,0,0,0}, vb = {0,0,0,0};
      if (m0 + row < M) va = *(const uint4*)(A + (m0 + row) * lda + k + sg);
      if (n0 + row < N) vb = *(const uint4*)(B + (n0 + row) * ldb + kb + sg);
      pa[p] = va; pb[p] = vb;
    }
  }

  f32x4 acc[4][4];
#pragma unroll
  for (int i = 0; i < 4; ++i)
#pragma unroll
    for (int j = 0; j < 4; ++j) { f32x4 zz = {0.f,0.f,0.f,0.f}; acc[i][j] = zz; }

  for (int it = 0; it < nIt; ++it) {
#pragma unroll
    for (int p = 0; p < 2; ++p) {
      *(uint4*)&As[p * 64 + rr][sg] = pa[p];
      *(uint4*)&Bs[p * 64 + rr][sg] = pb[p];
    }
    __syncthreads();
    if (it + 1 < nIt) {
      long k = kbeg + (long)(it + 1) * 32;
      long kb = bmod ? (k & (bmod - 1)) : k;
#pragma unroll
      for (int p = 0; p < 2; ++p) {
        int row = p * 64 + rr;
        uint4 va = {0,0,0,0}, vb = {0,0,0,0};
        if (m0 + row < M) va = *(const uint4*)(A + (m0 + row) * lda + k + sg);
        if (n0 + row < N) vb = *(const uint4*)(B + (n0 + row) * ldb + kb + sg);
        pa[p] = va; pb[p] = vb;
      }
    }
    f16x8 af[4], bf[4];
#pragma unroll
    for (int i = 0; i < 4; ++i) af[i] = *(const f16x8*)&As[wm + i*16 + lc][lr * 8];
#pragma unroll
    for (int j = 0; j < 4; ++j) bf[j] = *(const f16x8*)&Bs[wn + j*16 + lc][lr * 8];
#pragma unroll
    for (int i = 0; i < 4; ++i)
#pragma unroll
      for (int j = 0; j < 4; ++j)
        acc[i][j] = __builtin_amdgcn_mfma_f32_16x16x32_f16(af[i], bf[j], acc[i][j], 0, 0, 0);
    __syncthreads();
  }

  if (outF)  outF  += (long)batch * sF + (long)slice * sSl;
  if (outH)  outH  += (long)batch * sH;
  if (outH2) outH2 += (long)batch * sH2;
  if (out2)  out2  += (long)batch * s2;
#pragma unroll
  for (int i = 0; i < 4; ++i)
#pragma unroll
    for (int j = 0; j < 4; ++j)
#pragma unroll
      for (int r = 0; r < 4; ++r) {
        long row = m0 + wm + i * 16 + lr * 4 + r;
        long col = n0 + wn + j * 16 + lc;
        if (row < M && col < N) {
          float v = acc[i][j][r];
          if (bias1) v += bias1[col];
          if (bias2) v += bias2[col];
          if (act)   v = tanhf(v);
          if (outF) {
            long fc = ilv ? ((col & 1023) * 4 + (col >> 10)) : col;
            outF[row * ldF + fc] = v;
          }
          if (outH)  outH[row * ldH + col] = (f16)v;
          if (outH2) outH2[row * ldH2 + col] = (f16)v;
          if (out2) {
            f16 hi = (f16)v;
            out2[row * ld2 + col]        = hi;
            out2[row * ld2 + 1024 + col] = (f16)(v - (float)hi);
          }
        }
      }
}

// ---------------------------------------------------------------------------
// Monotonic grid barrier (counter never resets; target = gen * nblocks).
__device__ __forceinline__ void grid_barrier(int* bar, int target) {
  __threadfence();                 // release: drain stores, write back L2
  __syncthreads();
  if (threadIdx.x == 0) {
    __hip_atomic_fetch_add(bar, 1, __ATOMIC_RELEASE, __HIP_MEMORY_SCOPE_AGENT);
    while (__hip_atomic_load(bar, __ATOMIC_ACQUIRE, __HIP_MEMORY_SCOPE_AGENT) < target)
      __builtin_amdgcn_s_sleep(1);
  }
  __syncthreads();
  __threadfence();                 // acquire: invalidate stale cache lines
}

// ---------------------------------------------------------------------------
// Persistent LSTM: all 128 steps in one launch. 128 blocks; block owns 8
// h-indices (j0..j0+7) x 4 gates x 32 batches. Whh slice (32 rows = 64 KB)
// preloaded in LDS; c carried in registers (1/thread); grid barrier per step.
__global__ __launch_bounds__(256) void k_lstm_all(
    const f16* __restrict__ Whh,          // (4096,1024)
    const float* __restrict__ nt_table,   // (200,1024,4) gate-interleaved
    const float* __restrict__ prod_gates, // (32,1024,4) gate-interleaved
    const int* __restrict__ nt_ids,       // (128,32)
    const float* __restrict__ c0,         // (32,1024)
    f16* __restrict__ st,                 // (32,129,1024)
    f16* __restrict__ q2,                 // (4096,2048) hi|lo
    f16* __restrict__ X,                  // (4096,3072)
    f16* __restrict__ Y1,                 // (4096,2048)
    int* __restrict__ bar)
{
  __shared__ __align__(16) f16 whh_s[32][1032];
  __shared__ __align__(16) f16 hs[32][1032];
  __shared__ float partial[4][32][33];
  const int tid = threadIdx.x;
  const int w = tid >> 6, lane = tid & 63;
  const int lr = lane >> 4, lc = lane & 15;
  const int j0 = blockIdx.x * 8;
  const int nblk = gridDim.x;

  // preload Whh slice: LDS row r=(g*8+jj) <- global row g*1024 + j0 + jj
  for (int i = tid; i < 32 * 128; i += 256) {
    int r = i >> 7, c8 = i & 127;
    int g = r >> 3, jj = r & 7;
    *(uint4*)&whh_s[r][c8 * 8] =
        *(const uint4*)(Whh + ((long)g * 1024 + j0 + jj) * 1024 + c8 * 8);
  }
  const int b_own = tid & 31, jj_own = tid >> 5;
  const int j_own = j0 + jj_own;
  float c_reg = c0[(long)b_own * 1024 + j_own];

  for (int t = 0; t < TT; ++t) {
    // stage h_t (also covers the Whh-preload sync at t=0)
    for (int i = tid; i < 32 * 128; i += 256) {
      int b = i >> 7, c8 = i & 127;
      *(uint4*)&hs[b][c8 * 8] = *(const uint4*)&st[((long)b * 129 + t) * 1024 + c8 * 8];
    }
    __syncthreads();

    // wave w handles K chunk [w*256, w*256+256): 8 kt x (2x2) 16x16x32 MFMA
    f32x4 acc[2][2];
#pragma unroll
    for (int i = 0; i < 2; ++i)
#pragma unroll
      for (int j = 0; j < 2; ++j) { f32x4 zz = {0.f,0.f,0.f,0.f}; acc[i][j] = zz; }
#pragma unroll
    for (int kt = 0; kt < 8; ++kt) {
      int k = w * 256 + kt * 32 + lr * 8;
      f16x8 a0 = *(const f16x8*)&hs[lc][k];
      f16x8 a1 = *(const f16x8*)&hs[16 + lc][k];
      f16x8 b0 = *(const f16x8*)&whh_s[lc][k];
      f16x8 b1 = *(const f16x8*)&whh_s[16 + lc][k];
      acc[0][0] = __builtin_amdgcn_mfma_f32_16x16x32_f16(a0, b0, acc[0][0], 0, 0, 0);
      acc[0][1] = __builtin_amdgcn_mfma_f32_16x16x32_f16(a0, b1, acc[0][1], 0, 0, 0);
      acc[1][0] = __builtin_amdgcn_mfma_f32_16x16x32_f16(a1, b0, acc[1][0], 0, 0, 0);
      acc[1][1] = __builtin_amdgcn_mfma_f32_16x16x32_f16(a1, b1, acc[1][1], 0, 0, 0);
    }
    // partial[w][gaterow][batch] (stride 33 breaks conflicts)
#pragma unroll
    for (int mi = 0; mi < 2; ++mi)
#pragma unroll
      for (int ni = 0; ni < 2; ++ni)
#pragma unroll
        for (int r = 0; r < 4; ++r)
          partial[w][ni * 16 + lc][mi * 16 + lr * 4 + r] = acc[mi][ni][r];
    __syncthreads();

    // reduce 4 K-slices + LSTM cell; thread owns (b_own, jj_own)
    float g4[4];
#pragma unroll
    for (int g = 0; g < 4; ++g) {
      int rrow = g * 8 + jj_own;
      g4[g] = partial[0][rrow][b_own] + partial[1][rrow][b_own] +
              partial[2][rrow][b_own] + partial[3][rrow][b_own];
    }
    int nid = nt_ids[t * 32 + b_own];
    float4 nt4 = *(const float4*)(nt_table + (long)nid * 4096 + j_own * 4);
    float4 pg4 = *(const float4*)(prod_gates + (long)b_own * 4096 + j_own * 4);
    float ii = sigmoidf_(g4[0] + nt4.x + pg4.x);
    float ff = sigmoidf_(g4[1] + nt4.y + pg4.y);
    float gg = tanhf(g4[2] + nt4.z + pg4.z);
    float oo = sigmoidf_(g4[3] + nt4.w + pg4.w);
    c_reg = ff * c_reg + ii * gg;
    float hn = oo * tanhf(c_reg);
    f16 hi = (f16)hn;
    st[((long)b_own * 129 + t + 1) * 1024 + j_own] = hi;
    long row = (long)b_own * 128 + t;
    q2[row * 2048 + j_own]        = hi;
    q2[row * 2048 + 1024 + j_own] = (f16)(hn - (float)hi);
    X[row * 3072 + j_own]         = hi;
    Y1[row * 2048 + 1024 + j_own] = hi;

    if (t + 1 < TT) grid_barrier(bar, (t + 1) * nblk);
  }
}

// ---------------------------------------------------------------------------
// Row softmax over 512 cols of sum of 4 fp32 planes -> fp16. One block/row.
__global__ __launch_bounds__(256) void k_softmax4(const float* __restrict__ p,
                                                  long pstride,
                                                  f16* __restrict__ out) {
  long row = blockIdx.x;
  const float* p0 = p + row * 512;
  out += row * 512;
  const int tid = threadIdx.x, w = tid >> 6, lane = tid & 63;
  float vx = 0.f, vy = 0.f;
#pragma unroll
  for (int s = 0; s < 4; ++s) {
    float2 a = ((const float2*)(p0 + s * pstride))[tid];
    vx += a.x; vy += a.y;
  }
  float m = fmaxf(vx, vy);
#pragma unroll
  for (int off = 32; off; off >>= 1) m = fmaxf(m, __shfl_xor(m, off));
  __shared__ float red[8];
  if (lane == 0) red[w] = m;
  __syncthreads();
  m = fmaxf(fmaxf(red[0], red[1]), fmaxf(red[2], red[3]));
  float e0 = __expf(vx - m), e1 = __expf(vy - m);
  float s2 = e0 + e1;
#pragma unroll
  for (int off = 32; off; off >>= 1) s2 += __shfl_xor(s2, off);
  if (lane == 0) red[4 + w] = s2;
  __syncthreads();
  s2 = red[4] + red[5] + red[6] + red[7];
  float inv = 1.0f / s2;
  out[tid * 2]     = (f16)(e0 * inv);
  out[tid * 2 + 1] = (f16)(e1 * inv);
}

// ---------------------------------------------------------------------------
extern "C" void kernel_launch(void* const* d_in, const int* in_sizes, int n_in,
                              void* d_out, int out_size, void* d_ws, size_t ws_size,
                              hipStream_t stream)
{
  const int*   init_prod = (const int*)d_in[0];
  const int*   nt_ids    = (const int*)d_in[1];
  const float* h0   = (const float*)d_in[2];
  const float* c0   = (const float*)d_in[3];
  const float* nl   = (const float*)d_in[4];
  const float* env  = (const float*)d_in[5];
  const float* nt_emb   = (const float*)d_in[6];
  const float* rule_emb = (const float*)d_in[7];
  const float* W_ih = (const float*)d_in[8];
  const float* W_hh = (const float*)d_in[9];
  const float* b_ih = (const float*)d_in[10];
  const float* b_hh = (const float*)d_in[11];
  const float* Wz   = (const float*)d_in[12];
  const float* bz   = (const float*)d_in[13];
  const float* We   = (const float*)d_in[14];
  const float* be   = (const float*)d_in[15];
  const float* Wc   = (const float*)d_in[16];
  const float* bc   = (const float*)d_in[17];
  float* out = (float*)d_out;
  (void)in_sizes; (void)n_in; (void)out_size; (void)ws_size;

  size_t off = 0;
  auto carve = [&](size_t bytes) {
    char* p = (char*)d_ws + off;
    off += (bytes + 255) & ~(size_t)255;
    return (void*)p;
  };
  f16*   Whh_h   = (f16*)carve(4096L * 1024 * 2);
  f16*   Wz_h    = (f16*)carve(1024L * 2048 * 2);
  f16*   We_h    = (f16*)carve(1024L * 2048 * 2);
  f16*   Wc_h    = (f16*)carve(1024L * 3072 * 2);
  f16*   nte_h   = (f16*)carve(200L * 1024 * 2);
  f16*   prod_h  = (f16*)carve(32L * 1024 * 2);
  float* nt_table   = (float*)carve(200L * 4096 * 4);   // gate-interleaved
  float* prod_gates = (float*)carve(32L * 4096 * 4);    // gate-interleaved
  f16*   st_hi   = (f16*)carve(32L * 129 * 1024 * 2);
  f16*   q2      = (f16*)carve(4096L * 2048 * 2);   // query hi|lo (h, then zt)
  f16*   X       = (f16*)carve(4096L * 3072 * 2);   // [h | zt | et] for ct GEMM
  f16*   Y1      = (f16*)carve(4096L * 2048 * 2);   // [mix1 | h]  for zt GEMM
  f16*   Y2      = (f16*)carve(4096L * 2048 * 2);   // [mix2 | zt] for et GEMM
  f16*   ctx_h   = (f16*)carve(32L * 512 * 1024 * 2);
  f16*   ctxT    = (f16*)carve(32L * 1024 * 512 * 2);
  float* scoresP = (float*)carve(4L * 32 * 128 * 512 * 4);  // 4 split-K planes
  f16*   attn    = (f16*)carve(4096L * 512 * 2);
  int*   bar     = (int*)carve(256);
  f16*   Wih_h   = (f16*)X;   // alias: Wih dead before LSTM writes X

  auto f2h = [&](const float* src, f16* dst, long n) {
    long n4 = n / 4;
    k_f2h<<<dim3((unsigned)((n4 + 255) / 256)), dim3(256), 0, stream>>>(src, dst, n4);
  };
  f2h(W_ih, Wih_h, 4096L * 2048);
  f2h(W_hh, Whh_h, 4096L * 1024);
  f2h(Wz,   Wz_h,  1024L * 2048);
  f2h(We,   We_h,  1024L * 2048);
  f2h(Wc,   Wc_h,  1024L * 3072);
  f2h(nt_emb, nte_h, 200L * 1024);
  k_gather_prod<<<dim3(128), dim3(256), 0, stream>>>(rule_emb, init_prod, prod_h);
  k_h0<<<dim3(128), dim3(256), 0, stream>>>(h0, st_hi);
  k_zero<<<dim3(1), dim3(64), 0, stream>>>(bar);

  auto gemm = [&](const f16* A, long lda, long sA,
                  const f16* B, long ldb, long sB,
                  float* oF, long ldF, long sF, long sSl,
                  f16* oH, long ldH, long sH,
                  f16* oH2, long ldH2, long sH2,
                  f16* o2, long ld2, long s2,
                  const float* b1, const float* b2,
                  int M, int N, int K, int act, int bmod, int zdiv, int ilv,
                  int batch) {
    dim3 grid((unsigned)((M + 127) / 128), (unsigned)((N + 127) / 128),
              (unsigned)(batch * zdiv));
    k_gemm<<<grid, dim3(256), 0, stream>>>(A, lda, sA, B, ldb, sB,
                                           oF, ldF, sF, sSl, oH, ldH, sH,
                                           oH2, ldH2, sH2, o2, ld2, s2,
                                           b1, b2, M, N, K, act, bmod, zdiv, ilv);
  };
  const long SPL = 32L * 128 * 512;   // split-K plane stride (floats)

  // gate tables (gate-interleaved fp32 layout via ilv=1)
  gemm(nte_h, 1024, 0, Wih_h, 2048, 0, nt_table, 4096, 0, 0,
       nullptr,0,0, nullptr,0,0, nullptr,0,0, nullptr, nullptr,
       200, 4096, 1024, 0, 0, 1, 1, 1);
  gemm(prod_h, 1024, 0, Wih_h + 1024, 2048, 0, prod_gates, 4096, 0, 0,
       nullptr,0,0, nullptr,0,0, nullptr,0,0, b_ih, b_hh,
       32, 4096, 1024, 0, 0, 1, 1, 1);

  // persistent LSTM: one dispatch, 128 co-resident blocks, grid barrier/step
  k_lstm_all<<<dim3(LSTM_BLOCKS), dim3(256), 0, stream>>>(
      Whh_h, nt_table, prod_gates, nt_ids, c0, st_hi, q2, X, Y1, bar);

  // --- attention over nl ---
  k_transpose<<<dim3(16, 32, 32), dim3(256), 0, stream>>>(nl, ctxT, ctx_h);
  gemm(q2, 2048, 128L * 2048, ctx_h, 1024, 512L * 1024,
       scoresP, 512, 128L * 512, SPL, nullptr,0,0, nullptr,0,0, nullptr,0,0,
       nullptr, nullptr, 128, 512, 2048, 0, 1024, 4, 0, 32);
  k_softmax4<<<dim3(4096), dim3(256), 0, stream>>>(scoresP, SPL, attn);
  gemm(attn, 512, 128L * 512, ctxT, 512, 1024L * 512,
       nullptr,0,0,0, Y1, 2048, 128L * 2048, nullptr,0,0, nullptr,0,0,
       nullptr, nullptr, 128, 1024, 512, 0, 0, 1, 0, 32);
  // zt = tanh(Y1=[mix1|h] @ Wz^T + bz) -> X[:,1024:2048), Y2[:,1024:2048), q2
  gemm(Y1, 2048, 0, Wz_h, 2048, 0,
       nullptr,0,0,0, X + 1024, 3072, 0, Y2 + 1024, 2048, 0, q2, 2048, 0,
       bz, nullptr, 4096, 1024, 2048, 1, 0, 1, 0, 1);

  // --- attention over env ---
  k_transpose<<<dim3(16, 32, 32), dim3(256), 0, stream>>>(env, ctxT, ctx_h);
  gemm(q2, 2048, 128L * 2048, ctx_h, 1024, 512L * 1024,
       scoresP, 512, 128L * 512, SPL, nullptr,0,0, nullptr,0,0, nullptr,0,0,
       nullptr, nullptr, 128, 512, 2048, 0, 1024, 4, 0, 32);
  k_softmax4<<<dim3(4096), dim3(256), 0, stream>>>(scoresP, SPL, attn);
  gemm(attn, 512, 128L * 512, ctxT, 512, 1024L * 512,
       nullptr,0,0,0, Y2, 2048, 128L * 2048, nullptr,0,0, nullptr,0,0,
       nullptr, nullptr, 128, 1024, 512, 0, 0, 1, 0, 32);
  // et = tanh(Y2=[mix2|zt] @ We^T + be) -> X[:,2048:3072)
  gemm(Y2, 2048, 0, We_h, 2048, 0,
       nullptr,0,0,0, X + 2048, 3072, 0, nullptr,0,0, nullptr,0,0,
       be, nullptr, 4096, 1024, 2048, 1, 0, 1, 0, 1);

  // --- ct = tanh(X=[h|zt|et] @ Wc^T + bc) -> d_out (T,B,H) ---
  gemm(X, 3072, 128L * 3072, Wc_h, 3072, 0,
       out, 32L * 1024, 1024, 0, nullptr,0,0, nullptr,0,0, nullptr,0,0,
       bc, nullptr, 128, 1024, 3072, 1, 0, 1, 0, 32);
}

// Round 5
// 1682.971 us; speedup vs baseline: 3.3148x; 3.3148x over previous
//
#include <hip/hip_runtime.h>
#include <hip/hip_bf16.h>

typedef _Float16 f16;
typedef __attribute__((ext_vector_type(8))) _Float16 f16x8;
typedef __attribute__((ext_vector_type(4))) float f32x4;

#define TT 128
#define LSTM_BLOCKS 128

__device__ __forceinline__ float sigmoidf_(float x) { return 1.0f / (1.0f + __expf(-x)); }

// ---------------------------------------------------------------------------
// fp32 -> fp16 convert (n multiple of 4)
__global__ __launch_bounds__(256) void k_f2h(const float* __restrict__ in,
                                             f16* __restrict__ out, long n4) {
  long i = (long)blockIdx.x * 256 + threadIdx.x;
  if (i >= n4) return;
  float4 v = ((const float4*)in)[i];
  out[i*4+0] = (f16)v.x; out[i*4+1] = (f16)v.y;
  out[i*4+2] = (f16)v.z; out[i*4+3] = (f16)v.w;
}

// gather rule_emb rows for init_prod -> fp16 (32 x 1024)
__global__ __launch_bounds__(256) void k_gather_prod(const float* __restrict__ rule_emb,
                                                     const int* __restrict__ init_prod,
                                                     f16* __restrict__ out) {
  int i = blockIdx.x * 256 + threadIdx.x;
  int b = i >> 10, k = i & 1023;
  out[i] = (f16)rule_emb[(long)init_prod[b] * 1024 + k];
}

// h0 -> fp16 into st slot 0 (st layout: [b][129][1024])
__global__ __launch_bounds__(256) void k_h0(const float* __restrict__ h0,
                                            f16* __restrict__ st) {
  int i = blockIdx.x * 256 + threadIdx.x;
  int b = i >> 10, k = i & 1023;
  st[(long)b * 129 * 1024 + k] = (f16)h0[i];
}

__global__ __launch_bounds__(256) void k_zero(int* p, int n) {
  for (int i = threadIdx.x; i < n; i += 256) p[i] = 0;
}

// (B, L=512, H=1024) fp32 -> outT (B, H, L) f16  AND  outN (B, L, H) f16
__global__ __launch_bounds__(256) void k_transpose(const float* __restrict__ in,
                                                   f16* __restrict__ outT,
                                                   f16* __restrict__ outN) {
  __shared__ float tile[32][33];
  const int b  = blockIdx.z;
  const int l0 = blockIdx.x * 32, h0 = blockIdx.y * 32;
  in   += (long)b * 512 * 1024;
  outT += (long)b * 1024 * 512;
  outN += (long)b * 512 * 1024;
  const int c = threadIdx.x & 31, r = threadIdx.x >> 5;
#pragma unroll
  for (int p = 0; p < 4; ++p) {
    float v = in[(long)(l0 + r + p*8) * 1024 + h0 + c];
    tile[r + p*8][c] = v;
    outN[(long)(l0 + r + p*8) * 1024 + h0 + c] = (f16)v;
  }
  __syncthreads();
#pragma unroll
  for (int p = 0; p < 4; ++p)
    outT[(long)(h0 + r + p*8) * 512 + l0 + c] = (f16)tile[c][r + p*8];
}

// ---------------------------------------------------------------------------
// fp16 MFMA GEMM: C[M,N] = act( A[M,K] @ B[N,K]^T + bias1 + bias2 )
// 128x128 tile, BK=32, register-prefetch double buffer.
// bmod: B K-index wraps mod bmod. zdiv: split-K, partials at outF+slice*sSl.
// ilv: outF column remap col -> (col&1023)*4 + (col>>10)  (gate-interleave).
__global__ __launch_bounds__(256) void k_gemm(
    const f16* __restrict__ A, long lda, long sA,
    const f16* __restrict__ B, long ldb, long sB,
    float* __restrict__ outF, long ldF, long sF, long sSl,
    f16* __restrict__ outH, long ldH, long sH,
    f16* __restrict__ outH2, long ldH2, long sH2,
    f16* __restrict__ out2, long ld2, long s2,
    const float* __restrict__ bias1, const float* __restrict__ bias2,
    int M, int N, int K, int act, int bmod, int zdiv, int ilv)
{
  __shared__ __align__(16) f16 As[128][40];
  __shared__ __align__(16) f16 Bs[128][40];
  const int tid = threadIdx.x;
  const int w = tid >> 6, lane = tid & 63;
  const int wm = (w & 1) * 64, wn = (w >> 1) * 64;
  const int lr = lane >> 4, lc = lane & 15;
  const long m0 = (long)blockIdx.x * 128;
  const long n0 = (long)blockIdx.y * 128;
  int z = blockIdx.z, batch = z, slice = 0, Ks = K;
  if (zdiv > 1) { batch = z / zdiv; slice = z - batch * zdiv; Ks = K / zdiv; }
  const long kbeg = (long)slice * Ks;
  A += (long)batch * sA;
  B += (long)batch * sB;

  const int rr = tid >> 2, sg = (tid & 3) * 8;
  const int nIt = Ks / 32;

  uint4 pa[2], pb[2];
  {
    long k = kbeg;
    long kb = bmod ? (k & (bmod - 1)) : k;
#pragma unroll
    for (int p = 0; p < 2; ++p) {
      int row = p * 64 + rr;
      uint4 va = {0,0,0,0}, vb = {0,0,0,0};
      if (m0 + row < M) va = *(const uint4*)(A + (m0 + row) * lda + k + sg);
      if (n0 + row < N) vb = *(const uint4*)(B + (n0 + row) * ldb + kb + sg);
      pa[p] = va; pb[p] = vb;
    }
  }

  f32x4 acc[4][4];
#pragma unroll
  for (int i = 0; i < 4; ++i)
#pragma unroll
    for (int j = 0; j < 4; ++j) { f32x4 zz = {0.f,0.f,0.f,0.f}; acc[i][j] = zz; }

  for (int it = 0; it < nIt; ++it) {
#pragma unroll
    for (int p = 0; p < 2; ++p) {
      *(uint4*)&As[p * 64 + rr][sg] = pa[p];
      *(uint4*)&Bs[p * 64 + rr][sg] = pb[p];
    }
    __syncthreads();
    if (it + 1 < nIt) {
      long k = kbeg + (long)(it + 1) * 32;
      long kb = bmod ? (k & (bmod - 1)) : k;
#pragma unroll
      for (int p = 0; p < 2; ++p) {
        int row = p * 64 + rr;
        uint4 va = {0,0,0,0}, vb = {0,0,0,0};
        if (m0 + row < M) va = *(const uint4*)(A + (m0 + row) * lda + k + sg);
        if (n0 + row < N) vb = *(const uint4*)(B + (n0 + row) * ldb + kb + sg);
        pa[p] = va; pb[p] = vb;
      }
    }
    f16x8 af[4], bf[4];
#pragma unroll
    for (int i = 0; i < 4; ++i) af[i] = *(const f16x8*)&As[wm + i*16 + lc][lr * 8];
#pragma unroll
    for (int j = 0; j < 4; ++j) bf[j] = *(const f16x8*)&Bs[wn + j*16 + lc][lr * 8];
#pragma unroll
    for (int i = 0; i < 4; ++i)
#pragma unroll
      for (int j = 0; j < 4; ++j)
        acc[i][j] = __builtin_amdgcn_mfma_f32_16x16x32_f16(af[i], bf[j], acc[i][j], 0, 0, 0);
    __syncthreads();
  }

  if (outF)  outF  += (long)batch * sF + (long)slice * sSl;
  if (outH)  outH  += (long)batch * sH;
  if (outH2) outH2 += (long)batch * sH2;
  if (out2)  out2  += (long)batch * s2;
#pragma unroll
  for (int i = 0; i < 4; ++i)
#pragma unroll
    for (int j = 0; j < 4; ++j)
#pragma unroll
      for (int r = 0; r < 4; ++r) {
        long row = m0 + wm + i * 16 + lr * 4 + r;
        long col = n0 + wn + j * 16 + lc;
        if (row < M && col < N) {
          float v = acc[i][j][r];
          if (bias1) v += bias1[col];
          if (bias2) v += bias2[col];
          if (act)   v = tanhf(v);
          if (outF) {
            long fc = ilv ? ((col & 1023) * 4 + (col >> 10)) : col;
            outF[row * ldF + fc] = v;
          }
          if (outH)  outH[row * ldH + col] = (f16)v;
          if (outH2) outH2[row * ldH2 + col] = (f16)v;
          if (out2) {
            f16 hi = (f16)v;
            out2[row * ld2 + col]        = hi;
            out2[row * ld2 + 1024 + col] = (f16)(v - (float)hi);
          }
        }
      }
}

// ---------------------------------------------------------------------------
// Fence-free two-level grid barrier. Data written via write-through (sc0 sc1)
// stores to FRESH addresses each step -> readers' caches can't be stale, so
// only RELAXED control atomics are needed (no buffer_wbl2 / buffer_inv).
// cnt: 8 counters padded 128B apart; flag: monotone step counter.
__device__ __forceinline__ void grid_barrier(int* __restrict__ cnt,
                                             int* __restrict__ flag, int t) {
  __syncthreads();   // all threads' stores issued + vmcnt-drained (per-thread asm)
  if (threadIdx.x == 0)
    __hip_atomic_fetch_add(&cnt[(blockIdx.x & 7) * 32], 1,
                           __ATOMIC_RELAXED, __HIP_MEMORY_SCOPE_AGENT);
  if (blockIdx.x == 0) {
    if (threadIdx.x < 8) {
      const int tgt = (t + 1) * (LSTM_BLOCKS / 8);
      while (__hip_atomic_load(&cnt[threadIdx.x * 32],
                               __ATOMIC_RELAXED, __HIP_MEMORY_SCOPE_AGENT) < tgt)
        __builtin_amdgcn_s_sleep(2);
    }
    __syncthreads();
    if (threadIdx.x == 0)
      __hip_atomic_store(flag, t + 1, __ATOMIC_RELAXED, __HIP_MEMORY_SCOPE_AGENT);
  } else {
    if (threadIdx.x == 0) {
      while (__hip_atomic_load(flag, __ATOMIC_RELAXED,
                               __HIP_MEMORY_SCOPE_AGENT) <= t)
        __builtin_amdgcn_s_sleep(2);
    }
    __syncthreads();
  }
  asm volatile("" ::: "memory");   // compiler barrier: no load hoisting
}

// ---------------------------------------------------------------------------
// Persistent LSTM: all 128 steps in one launch. 128 blocks; block owns 8
// h-indices (j0..j0+7) x 4 gates x 32 batches. Whh slice (64 KB) in LDS.
// c in registers. h_{t+1} published via write-through stores + relaxed barrier.
__global__ __launch_bounds__(256) void k_lstm_all(
    const f16* __restrict__ Whh,          // (4096,1024)
    const float* __restrict__ nt_table,   // (200,1024,4) gate-interleaved
    const float* __restrict__ prod_gates, // (32,1024,4) gate-interleaved
    const int* __restrict__ nt_ids,       // (128,32)
    const float* __restrict__ c0,         // (32,1024)
    f16* __restrict__ st,                 // (32,129,1024)
    f16* __restrict__ q2,                 // (4096,2048) hi|lo
    f16* __restrict__ X,                  // (4096,3072)
    f16* __restrict__ Y1,                 // (4096,2048)
    int* __restrict__ cnt, int* __restrict__ flag)
{
  __shared__ __align__(16) f16 whh_s[32][1032];
  __shared__ __align__(16) f16 hs[32][1032];
  __shared__ float partial[4][32][33];
  const int tid = threadIdx.x;
  const int w = tid >> 6, lane = tid & 63;
  const int lr = lane >> 4, lc = lane & 15;
  const int j0 = blockIdx.x * 8;

  // preload Whh slice: LDS row r=(g*8+jj) <- global row g*1024 + j0 + jj
  for (int i = tid; i < 32 * 128; i += 256) {
    int r = i >> 7, c8 = i & 127;
    int g = r >> 3, jj = r & 7;
    *(uint4*)&whh_s[r][c8 * 8] =
        *(const uint4*)(Whh + ((long)g * 1024 + j0 + jj) * 1024 + c8 * 8);
  }
  // thread owns (b_own, jj_own); 8 consecutive lanes share b -> coalesced
  const int b_own = tid >> 3, jj_own = tid & 7;
  const int j_own = j0 + jj_own;
  float c_reg = c0[(long)b_own * 1024 + j_own];

  for (int t = 0; t < TT; ++t) {
    // stage h_t (normal cached loads; fresh lines each step)
    for (int i = tid; i < 32 * 128; i += 256) {
      int b = i >> 7, c8 = i & 127;
      *(uint4*)&hs[b][c8 * 8] = *(const uint4*)&st[((long)b * 129 + t) * 1024 + c8 * 8];
    }
    __syncthreads();   // also covers whh_s preload at t=0

    // wave w: K chunk [w*256, w*256+256): 8 kt x (2x2) 16x16x32 MFMA
    f32x4 acc[2][2];
#pragma unroll
    for (int i = 0; i < 2; ++i)
#pragma unroll
      for (int j = 0; j < 2; ++j) { f32x4 zz = {0.f,0.f,0.f,0.f}; acc[i][j] = zz; }
#pragma unroll
    for (int kt = 0; kt < 8; ++kt) {
      int k = w * 256 + kt * 32 + lr * 8;
      f16x8 a0 = *(const f16x8*)&hs[lc][k];
      f16x8 a1 = *(const f16x8*)&hs[16 + lc][k];
      f16x8 b0 = *(const f16x8*)&whh_s[lc][k];
      f16x8 b1 = *(const f16x8*)&whh_s[16 + lc][k];
      acc[0][0] = __builtin_amdgcn_mfma_f32_16x16x32_f16(a0, b0, acc[0][0], 0, 0, 0);
      acc[0][1] = __builtin_amdgcn_mfma_f32_16x16x32_f16(a0, b1, acc[0][1], 0, 0, 0);
      acc[1][0] = __builtin_amdgcn_mfma_f32_16x16x32_f16(a1, b0, acc[1][0], 0, 0, 0);
      acc[1][1] = __builtin_amdgcn_mfma_f32_16x16x32_f16(a1, b1, acc[1][1], 0, 0, 0);
    }
#pragma unroll
    for (int mi = 0; mi < 2; ++mi)
#pragma unroll
      for (int ni = 0; ni < 2; ++ni)
#pragma unroll
        for (int r = 0; r < 4; ++r)
          partial[w][ni * 16 + lc][mi * 16 + lr * 4 + r] = acc[mi][ni][r];
    __syncthreads();

    // reduce 4 K-slices + LSTM cell
    float g4[4];
#pragma unroll
    for (int g = 0; g < 4; ++g) {
      int rrow = g * 8 + jj_own;
      g4[g] = partial[0][rrow][b_own] + partial[1][rrow][b_own] +
              partial[2][rrow][b_own] + partial[3][rrow][b_own];
    }
    int nid = nt_ids[t * 32 + b_own];
    float4 nt4 = *(const float4*)(nt_table + (long)nid * 4096 + j_own * 4);
    float4 pg4 = *(const float4*)(prod_gates + (long)b_own * 4096 + j_own * 4);
    float ii = sigmoidf_(g4[0] + nt4.x + pg4.x);
    float ff = sigmoidf_(g4[1] + nt4.y + pg4.y);
    float gg = tanhf(g4[2] + nt4.z + pg4.z);
    float oo = sigmoidf_(g4[3] + nt4.w + pg4.w);
    c_reg = ff * c_reg + ii * gg;
    float hn = oo * tanhf(c_reg);
    f16 hi = (f16)hn;
    long row = (long)b_own * 128 + t;
    q2[row * 2048 + j_own]        = hi;                      // cached stores:
    q2[row * 2048 + 1024 + j_own] = (f16)(hn - (float)hi);   //  consumed post-kernel
    X[row * 3072 + j_own]         = hi;
    Y1[row * 2048 + 1024 + j_own] = hi;
    // write-through publish of h_{t+1} + drain THIS thread's stores
    {
      union { f16 h; unsigned short u; } cv; cv.h = hi;
      unsigned v32 = cv.u;
      const f16* pst = st + ((long)b_own * 129 + t + 1) * 1024 + j_own;
      asm volatile("global_store_short %0, %1, off sc0 sc1\n\t"
                   "s_waitcnt vmcnt(0)" :: "v"(pst), "v"(v32) : "memory");
    }
    if (t + 1 < TT) grid_barrier(cnt, flag, t);
  }
}

// ---------------------------------------------------------------------------
// Row softmax over 512 cols of sum of 4 fp32 planes -> fp16. One block/row.
__global__ __launch_bounds__(256) void k_softmax4(const float* __restrict__ p,
                                                  long pstride,
                                                  f16* __restrict__ out) {
  long row = blockIdx.x;
  const float* p0 = p + row * 512;
  out += row * 512;
  const int tid = threadIdx.x, w = tid >> 6, lane = tid & 63;
  float vx = 0.f, vy = 0.f;
#pragma unroll
  for (int s = 0; s < 4; ++s) {
    float2 a = ((const float2*)(p0 + s * pstride))[tid];
    vx += a.x; vy += a.y;
  }
  float m = fmaxf(vx, vy);
#pragma unroll
  for (int off = 32; off; off >>= 1) m = fmaxf(m, __shfl_xor(m, off));
  __shared__ float red[8];
  if (lane == 0) red[w] = m;
  __syncthreads();
  m = fmaxf(fmaxf(red[0], red[1]), fmaxf(red[2], red[3]));
  float e0 = __expf(vx - m), e1 = __expf(vy - m);
  float s2 = e0 + e1;
#pragma unroll
  for (int off = 32; off; off >>= 1) s2 += __shfl_xor(s2, off);
  if (lane == 0) red[4 + w] = s2;
  __syncthreads();
  s2 = red[4] + red[5] + red[6] + red[7];
  float inv = 1.0f / s2;
  out[tid * 2]     = (f16)(e0 * inv);
  out[tid * 2 + 1] = (f16)(e1 * inv);
}

// ---------------------------------------------------------------------------
extern "C" void kernel_launch(void* const* d_in, const int* in_sizes, int n_in,
                              void* d_out, int out_size, void* d_ws, size_t ws_size,
                              hipStream_t stream)
{
  const int*   init_prod = (const int*)d_in[0];
  const int*   nt_ids    = (const int*)d_in[1];
  const float* h0   = (const float*)d_in[2];
  const float* c0   = (const float*)d_in[3];
  const float* nl   = (const float*)d_in[4];
  const float* env  = (const float*)d_in[5];
  const float* nt_emb   = (const float*)d_in[6];
  const float* rule_emb = (const float*)d_in[7];
  const float* W_ih = (const float*)d_in[8];
  const float* W_hh = (const float*)d_in[9];
  const float* b_ih = (const float*)d_in[10];
  const float* b_hh = (const float*)d_in[11];
  const float* Wz   = (const float*)d_in[12];
  const float* bz   = (const float*)d_in[13];
  const float* We   = (const float*)d_in[14];
  const float* be   = (const float*)d_in[15];
  const float* Wc   = (const float*)d_in[16];
  const float* bc   = (const float*)d_in[17];
  float* out = (float*)d_out;
  (void)in_sizes; (void)n_in; (void)out_size; (void)ws_size;

  size_t off = 0;
  auto carve = [&](size_t bytes) {
    char* p = (char*)d_ws + off;
    off += (bytes + 255) & ~(size_t)255;
    return (void*)p;
  };
  f16*   Whh_h   = (f16*)carve(4096L * 1024 * 2);
  f16*   Wz_h    = (f16*)carve(1024L * 2048 * 2);
  f16*   We_h    = (f16*)carve(1024L * 2048 * 2);
  f16*   Wc_h    = (f16*)carve(1024L * 3072 * 2);
  f16*   nte_h   = (f16*)carve(200L * 1024 * 2);
  f16*   prod_h  = (f16*)carve(32L * 1024 * 2);
  float* nt_table   = (float*)carve(200L * 4096 * 4);   // gate-interleaved
  float* prod_gates = (float*)carve(32L * 4096 * 4);    // gate-interleaved
  f16*   st_hi   = (f16*)carve(32L * 129 * 1024 * 2);
  f16*   q2      = (f16*)carve(4096L * 2048 * 2);   // query hi|lo (h, then zt)
  f16*   X       = (f16*)carve(4096L * 3072 * 2);   // [h | zt | et] for ct GEMM
  f16*   Y1      = (f16*)carve(4096L * 2048 * 2);   // [mix1 | h]  for zt GEMM
  f16*   Y2      = (f16*)carve(4096L * 2048 * 2);   // [mix2 | zt] for et GEMM
  f16*   ctx_h   = (f16*)carve(32L * 512 * 1024 * 2);
  f16*   ctxT    = (f16*)carve(32L * 1024 * 512 * 2);
  float* scoresP = (float*)carve(4L * 32 * 128 * 512 * 4);  // 4 split-K planes
  f16*   attn    = (f16*)carve(4096L * 512 * 2);
  int*   bar     = (int*)carve(2048);   // 8 padded counters + flag
  f16*   Wih_h   = (f16*)X;   // alias: Wih dead before LSTM writes X

  auto f2h = [&](const float* src, f16* dst, long n) {
    long n4 = n / 4;
    k_f2h<<<dim3((unsigned)((n4 + 255) / 256)), dim3(256), 0, stream>>>(src, dst, n4);
  };
  f2h(W_ih, Wih_h, 4096L * 2048);
  f2h(W_hh, Whh_h, 4096L * 1024);
  f2h(Wz,   Wz_h,  1024L * 2048);
  f2h(We,   We_h,  1024L * 2048);
  f2h(Wc,   Wc_h,  1024L * 3072);
  f2h(nt_emb, nte_h, 200L * 1024);
  k_gather_prod<<<dim3(128), dim3(256), 0, stream>>>(rule_emb, init_prod, prod_h);
  k_h0<<<dim3(128), dim3(256), 0, stream>>>(h0, st_hi);
  k_zero<<<dim3(1), dim3(256), 0, stream>>>(bar, 512);

  auto gemm = [&](const f16* A, long lda, long sA,
                  const f16* B, long ldb, long sB,
                  float* oF, long ldF, long sF, long sSl,
                  f16* oH, long ldH, long sH,
                  f16* oH2, long ldH2, long sH2,
                  f16* o2, long ld2, long s2,
                  const float* b1, const float* b2,
                  int M, int N, int K, int act, int bmod, int zdiv, int ilv,
                  int batch) {
    dim3 grid((unsigned)((M + 127) / 128), (unsigned)((N + 127) / 128),
              (unsigned)(batch * zdiv));
    k_gemm<<<grid, dim3(256), 0, stream>>>(A, lda, sA, B, ldb, sB,
                                           oF, ldF, sF, sSl, oH, ldH, sH,
                                           oH2, ldH2, sH2, o2, ld2, s2,
                                           b1, b2, M, N, K, act, bmod, zdiv, ilv);
  };
  const long SPL = 32L * 128 * 512;   // split-K plane stride (floats)

  // gate tables (gate-interleaved fp32 layout via ilv=1)
  gemm(nte_h, 1024, 0, Wih_h, 2048, 0, nt_table, 4096, 0, 0,
       nullptr,0,0, nullptr,0,0, nullptr,0,0, nullptr, nullptr,
       200, 4096, 1024, 0, 0, 1, 1, 1);
  gemm(prod_h, 1024, 0, Wih_h + 1024, 2048, 0, prod_gates, 4096, 0, 0,
       nullptr,0,0, nullptr,0,0, nullptr,0,0, b_ih, b_hh,
       32, 4096, 1024, 0, 0, 1, 1, 1);

  // persistent LSTM: one dispatch, fence-free relaxed barrier per step
  k_lstm_all<<<dim3(LSTM_BLOCKS), dim3(256), 0, stream>>>(
      Whh_h, nt_table, prod_gates, nt_ids, c0, st_hi, q2, X, Y1,
      bar, bar + 8 * 32);

  // --- attention over nl ---
  k_transpose<<<dim3(16, 32, 32), dim3(256), 0, stream>>>(nl, ctxT, ctx_h);
  gemm(q2, 2048, 128L * 2048, ctx_h, 1024, 512L * 1024,
       scoresP, 512, 128L * 512, SPL, nullptr,0,0, nullptr,0,0, nullptr,0,0,
       nullptr, nullptr, 128, 512, 2048, 0, 1024, 4, 0, 32);
  k_softmax4<<<dim3(4096), dim3(256), 0, stream>>>(scoresP, SPL, attn);
  gemm(attn, 512, 128L * 512, ctxT, 512, 1024L * 512,
       nullptr,0,0,0, Y1, 2048, 128L * 2048, nullptr,0,0, nullptr,0,0,
       nullptr, nullptr, 128, 1024, 512, 0, 0, 1, 0, 32);
  // zt = tanh(Y1=[mix1|h] @ Wz^T + bz) -> X[:,1024:2048), Y2[:,1024:2048), q2
  gemm(Y1, 2048, 0, Wz_h, 2048, 0,
       nullptr,0,0,0, X + 1024, 3072, 0, Y2 + 1024, 2048, 0, q2, 2048, 0,
       bz, nullptr, 4096, 1024, 2048, 1, 0, 1, 0, 1);

  // --- attention over env ---
  k_transpose<<<dim3(16, 32, 32), dim3(256), 0, stream>>>(env, ctxT, ctx_h);
  gemm(q2, 2048, 128L * 2048, ctx_h, 1024, 512L * 1024,
       scoresP, 512, 128L * 512, SPL, nullptr,0,0, nullptr,0,0, nullptr,0,0,
       nullptr, nullptr, 128, 512, 2048, 0, 1024, 4, 0, 32);
  k_softmax4<<<dim3(4096), dim3(256), 0, stream>>>(scoresP, SPL, attn);
  gemm(attn, 512, 128L * 512, ctxT, 512, 1024L * 512,
       nullptr,0,0,0, Y2, 2048, 128L * 2048, nullptr,0,0, nullptr,0,0,
       nullptr, nullptr, 128, 1024, 512, 0, 0, 1, 0, 32);
  // et = tanh(Y2=[mix2|zt] @ We^T + be) -> X[:,2048:3072)
  gemm(Y2, 2048, 0, We_h, 2048, 0,
       nullptr,0,0,0, X + 2048, 3072, 0, nullptr,0,0, nullptr,0,0,
       be, nullptr, 4096, 1024, 2048, 1, 0, 1, 0, 1);

  // --- ct = tanh(X=[h|zt|et] @ Wc^T + bc) -> d_out (T,B,H) ---
  gemm(X, 3072, 128L * 3072, Wc_h, 3072, 0,
       out, 32L * 1024, 1024, 0, nullptr,0,0, nullptr,0,0, nullptr,0,0,
       bc, nullptr, 128, 1024, 3072, 1, 0, 1, 0, 32);
}